// Round 7
// baseline (248.489 us; speedup 1.0000x reference)
//
#include <hip/hip_runtime.h>

// KNRM round 7: q-in-LDS / d-in-registers role flip.
//  Phase 1 (knrm_norm): fp32 table -> bf16 rows padded to 320 cols + rnorm
//    computed FROM the rounded values (exact-match cosine == 1; kernel0
//    sigma=1e-4 requires this).
//  Phase 2 (knrm_main5): grid 2048 = batch(256, low bits -> XCD swizzle) x
//    g(8). Per block: stage the batch's 32 q rows to LDS ONCE (21 KB, one
//    barrier); each wave owns 16 d rows loaded DIRECT to registers as MFMA
//    B-fragments (10 x dwordx4/lane in flight, no LDS round trip, no cvt).
//    20 MFMAs cover 32q x 16d per wave. Gaussians on acc regs, shuffle-reduce
//    over the 16 d lanes, unique-writer stores pkq_part[b][32][32][11].
//    Scattered traffic: q 42 MB + d 84 MB (vs ~250 MB in R6).
//  Phase 3 (knrm_epi): sum 32 partials, log/mask/dot -> out[B].

#define B      256
#define BQ     32
#define BD     512
#define EDIM   300
#define KPAD   320
#define NK     11
#define NSEMI  32            // 512 / 16 d rows per wave
#define QSTR   328           // q_buf stride (halfwords): 164 words == 4 mod 32

typedef float floatx4 __attribute__((ext_vector_type(4)));
typedef short shortx8 __attribute__((ext_vector_type(8)));

__device__ __forceinline__ unsigned short f2bf(float f) {
    unsigned int u = __float_as_uint(f);
    return (unsigned short)((u + 0x7fffu + ((u >> 16) & 1u)) >> 16);  // RNE
}
__device__ __forceinline__ float bf2f(unsigned short h) {
    return __uint_as_float(((unsigned int)h) << 16);
}
__device__ __forceinline__ float sbc(float x) {   // force into SGPR
    return __uint_as_float(__builtin_amdgcn_readfirstlane(__float_as_uint(x)));
}

// ---------------- Phase 1: normalize / convert table ----------------
__global__ __launch_bounds__(256)
void knrm_norm(const float* __restrict__ emb, unsigned short* __restrict__ ebf,
               float* __restrict__ rnorm, int V)
{
    int r    = blockIdx.x * 16 + (threadIdx.x >> 4);
    int part = threadIdx.x & 15;
    if (r >= V) return;
    const float4* src = (const float4*)(emb + (size_t)r * EDIM);
    uint2*        dst = (uint2*)(ebf + (size_t)r * KPAD);
    float ss = 0.f;
    #pragma unroll
    for (int i = 0; i < 5; ++i) {
        int c = part + i * 16;            // 80 uint2 = 640 B row
        uint2 p = {0u, 0u};
        if (c < EDIM / 4) {
            float4 v = src[c];
            unsigned short h0 = f2bf(v.x), h1 = f2bf(v.y), h2 = f2bf(v.z), h3 = f2bf(v.w);
            p.x = (unsigned int)h0 | ((unsigned int)h1 << 16);
            p.y = (unsigned int)h2 | ((unsigned int)h3 << 16);
            float f0 = bf2f(h0), f1 = bf2f(h1), f2 = bf2f(h2), f3 = bf2f(h3);
            ss += f0 * f0 + f1 * f1 + f2 * f2 + f3 * f3;
        }
        dst[c] = p;                       // pad region [300,320) gets zeros
    }
    ss += __shfl_xor(ss, 1);
    ss += __shfl_xor(ss, 2);
    ss += __shfl_xor(ss, 4);
    ss += __shfl_xor(ss, 8);
    if (part == 0) rnorm[r] = 1.f / (sqrtf(ss) + 1e-13f);
}

// ---------------- Phase 2: gather + MFMA + Gaussians ----------------
__global__ __launch_bounds__(256, 5)
void knrm_main5(const int* __restrict__ qtok, const int* __restrict__ dtok,
                const unsigned short* __restrict__ ebf, const float* __restrict__ rnorm,
                const float* __restrict__ mu, const float* __restrict__ sigma,
                float* __restrict__ pkq_part)
{
    __shared__ unsigned short q_buf[BQ * QSTR];   // 20992 B
    __shared__ float rqs[BQ];

    const int tid  = threadIdx.x;
    const int lane = tid & 63;
    const int wv   = tid >> 6;
    const int b    = blockIdx.x & 255;    // XCD swizzle: batch's 8 blocks share XCD b%8
    const int g    = blockIdx.x >> 8;     // 0..7
    const int l16  = lane & 15;
    const int quad = lane >> 4;

    // this wave's 16 d rows: lane l16 owns row td
    const int td = dtok[b * BD + g * 64 + wv * 16 + l16];
    const float rd = rnorm[td];
    const float dm = (td > 0) ? 1.f : 0.f;

    // B-fragments direct from bf16 table: lane holds B[n=l16][k=quad*8+ks*32+j].
    // 4 quads of a row read consecutive 16B -> 64-B-line coalesced.
    const uint4* bsrc = (const uint4*)(ebf + (size_t)td * KPAD);
    shortx8 bfrag[10];
    #pragma unroll
    for (int ks = 0; ks < 10; ++ks)
        bfrag[ks] = *(const shortx8*)&bsrc[quad + ks * 4];

    // q reciprocal norms
    if (tid < BQ) rqs[tid] = rnorm[qtok[b * BQ + tid]];

    // stage the 32 q rows once: 8 threads/row x 5 dwordx4 (pre-zero-padded)
    {
        int row = tid >> 3, part = tid & 7;
        int tok = qtok[b * BQ + row];
        const uint4* src = (const uint4*)(ebf + (size_t)tok * KPAD);
        #pragma unroll
        for (int i = 0; i < 5; ++i) {
            int c = part + i * 8;
            *(uint4*)&q_buf[row * QSTR + c * 8] = src[c];
        }
    }
    __syncthreads();

    // gaussian constants in SGPRs (uniform)
    float mur[NK], cfr[NK];
    #pragma unroll
    for (int k = 0; k < NK; ++k) {
        float s = sbc(sigma[k]);
        mur[k] = sbc(mu[k]);
        cfr[k] = -0.5f / (s * s);
    }

    // A from LDS: A[m=l16][k=quad*8+...], two 16-row q slabs
    const unsigned short* a0 = &q_buf[l16 * QSTR + quad * 8];
    const unsigned short* a1 = a0 + 16 * QSTR;

    floatx4 acc0 = {0.f, 0.f, 0.f, 0.f};   // q rows 0..15
    floatx4 acc1 = {0.f, 0.f, 0.f, 0.f};   // q rows 16..31
    #pragma unroll
    for (int ks = 0; ks < 10; ++ks) {
        shortx8 aA = *(const shortx8*)(a0 + ks * 32);
        shortx8 aB = *(const shortx8*)(a1 + ks * 32);
        acc0 = __builtin_amdgcn_mfma_f32_16x16x32_bf16(aA, bfrag[ks], acc0, 0, 0, 0);
        acc1 = __builtin_amdgcn_mfma_f32_16x16x32_bf16(aB, bfrag[ks], acc1, 0, 0, 0);
    }

    // acc element r = S[q = slab*16 + quad*4 + r][d = this lane's td]
    const int semi = g * 4 + wv;          // 0..31
    float* dst = pkq_part + (size_t)(b * NSEMI + semi) * (BQ * NK);

    #pragma unroll
    for (int slab = 0; slab < 2; ++slab) {
        floatx4 acc = slab ? acc1 : acc0;
        #pragma unroll
        for (int r = 0; r < 4; ++r) {
            int q = slab * 16 + quad * 4 + r;
            float c0 = acc[r] * rqs[q] * rd;   // rqs[q]: quad-uniform -> LDS broadcast
            #pragma unroll
            for (int k = 0; k < NK; ++k) {
                float d0 = c0 - mur[k];
                float v = dm * __expf(cfr[k] * d0 * d0);
                v += __shfl_xor(v, 1);
                v += __shfl_xor(v, 2);
                v += __shfl_xor(v, 4);
                v += __shfl_xor(v, 8);
                if (l16 == 0) dst[q * NK + k] = v;   // unique writer per slot
            }
        }
    }
}

// ---------------- Phase 3: epilogue ----------------
__global__ __launch_bounds__(64)
void knrm_epi(const int* __restrict__ qtok, const float* __restrict__ dw,
              const float* __restrict__ db, const float* __restrict__ pkq_part,
              float* __restrict__ out)
{
    int b = blockIdx.x, lane = threadIdx.x;
    float sq = 0.f;
    if (lane < BQ) {
        int tok = qtok[b * BQ + lane];
        if (tok > 0) {
            #pragma unroll
            for (int k = 0; k < NK; ++k) {
                float s = 0.f;
                #pragma unroll
                for (int c = 0; c < NSEMI; ++c)
                    s += pkq_part[((size_t)(b * NSEMI + c) * BQ + lane) * NK + k];
                sq += __logf(fmaxf(s, 1e-10f)) * 0.01f * dw[k];
            }
        }
    }
    sq += __shfl_xor(sq, 1);
    sq += __shfl_xor(sq, 2);
    sq += __shfl_xor(sq, 4);
    sq += __shfl_xor(sq, 8);
    sq += __shfl_xor(sq, 16);
    sq += __shfl_xor(sq, 32);
    if (lane == 0) out[b] = sq + db[0];
}

extern "C" void kernel_launch(void* const* d_in, const int* in_sizes, int n_in,
                              void* d_out, int out_size, void* d_ws, size_t ws_size,
                              hipStream_t stream)
{
    const int*   qtok  = (const int*)d_in[0];
    const int*   dtok  = (const int*)d_in[1];
    const float* emb   = (const float*)d_in[2];
    const float* dw    = (const float*)d_in[3];
    const float* dbias = (const float*)d_in[4];
    const float* mu    = (const float*)d_in[5];
    const float* sg    = (const float*)d_in[6];
    float* out = (float*)d_out;

    const int V = in_sizes[2] / EDIM;   // 100000
    const size_t ebf_bytes = (size_t)V * KPAD * 2;   // 64 MB
    const size_t rn_bytes  = (size_t)V * 4;          // 0.4 MB

    unsigned short* ebf = (unsigned short*)d_ws;
    float* rnorm        = (float*)((char*)d_ws + ebf_bytes);
    float* pkq_part     = (float*)((char*)d_ws + ebf_bytes + rn_bytes);  // 11.5 MB

    knrm_norm<<<(V + 15) / 16, 256, 0, stream>>>(emb, ebf, rnorm, V);
    knrm_main5<<<B * 8, 256, 0, stream>>>(qtok, dtok, ebf, rnorm, mu, sg, pkq_part);
    knrm_epi<<<B, 64, 0, stream>>>(qtok, dw, dbias, pkq_part, out);
}

// Round 8
// 231.414 us; speedup vs baseline: 1.0738x; 1.0738x over previous
//
#include <hip/hip_runtime.h>

// KNRM round 8: amortized reduction + software-pipelined multi-chunk waves.
//  Phase 1 (knrm_norm): fp32 table -> bf16 rows padded to 320 cols + rnorm
//    computed FROM the rounded values (exact-match cosine == 1; kernel0
//    sigma=1e-4 requires this).
//  Phase 2 (knrm_main6): grid 512 = batch(256, low bits -> XCD swizzle) x
//    half(2). Block: stage 32 q rows to LDS once. Each wave owns a 16-d-row
//    lane-slice and iterates 4 chunk-steps (64 d rows per wave total),
//    d B-fragments double-buffered in registers (prefetch next step before
//    the 88-exp tail of the current step). Gaussian partials accumulate in
//    pk[2][4][11] registers across all 4 steps; ONE cross-lane reduce +
//    LDS-atomic combine + unique-writer store per block (8x fewer shuffle
//    ops than R5-R7, which re-reduced every chunk).
//  Phase 3 (knrm_epi): sum 2 partials, log/mask/dot -> out[B].

#define B      256
#define BQ     32
#define BD     512
#define EDIM   300
#define KPAD   320
#define NK     11
#define QSTR   328   // q_buf stride (halfwords): 164 words == 4 mod 32

typedef float floatx4 __attribute__((ext_vector_type(4)));
typedef short shortx8 __attribute__((ext_vector_type(8)));

__device__ __forceinline__ unsigned short f2bf(float f) {
    unsigned int u = __float_as_uint(f);
    return (unsigned short)((u + 0x7fffu + ((u >> 16) & 1u)) >> 16);  // RNE
}
__device__ __forceinline__ float bf2f(unsigned short h) {
    return __uint_as_float(((unsigned int)h) << 16);
}
__device__ __forceinline__ float sbc(float x) {   // force into SGPR
    return __uint_as_float(__builtin_amdgcn_readfirstlane(__float_as_uint(x)));
}

// ---------------- Phase 1: normalize / convert table ----------------
__global__ __launch_bounds__(256)
void knrm_norm(const float* __restrict__ emb, unsigned short* __restrict__ ebf,
               float* __restrict__ rnorm, int V)
{
    int r    = blockIdx.x * 16 + (threadIdx.x >> 4);
    int part = threadIdx.x & 15;
    if (r >= V) return;
    const float4* src = (const float4*)(emb + (size_t)r * EDIM);
    uint2*        dst = (uint2*)(ebf + (size_t)r * KPAD);
    float ss = 0.f;
    #pragma unroll
    for (int i = 0; i < 5; ++i) {
        int c = part + i * 16;            // 80 uint2 = 640 B row
        uint2 p = {0u, 0u};
        if (c < EDIM / 4) {
            float4 v = src[c];
            unsigned short h0 = f2bf(v.x), h1 = f2bf(v.y), h2 = f2bf(v.z), h3 = f2bf(v.w);
            p.x = (unsigned int)h0 | ((unsigned int)h1 << 16);
            p.y = (unsigned int)h2 | ((unsigned int)h3 << 16);
            float f0 = bf2f(h0), f1 = bf2f(h1), f2 = bf2f(h2), f3 = bf2f(h3);
            ss += f0 * f0 + f1 * f1 + f2 * f2 + f3 * f3;
        }
        dst[c] = p;                       // pad region [300,320) gets zeros
    }
    ss += __shfl_xor(ss, 1);
    ss += __shfl_xor(ss, 2);
    ss += __shfl_xor(ss, 4);
    ss += __shfl_xor(ss, 8);
    if (part == 0) rnorm[r] = 1.f / (sqrtf(ss) + 1e-13f);
}

// ---------------- Phase 2: pipelined gather + MFMA + Gaussians ----------------
__device__ __forceinline__ void load_frags(shortx8* bf, const unsigned short* __restrict__ ebf,
                                           int tok, int quad)
{
    const uint4* src = (const uint4*)(ebf + (size_t)tok * KPAD);
    #pragma unroll
    for (int ks = 0; ks < 10; ++ks)
        bf[ks] = *(const shortx8*)&src[quad + ks * 4];
}

__global__ __launch_bounds__(256)
void knrm_main6(const int* __restrict__ qtok, const int* __restrict__ dtok,
                const unsigned short* __restrict__ ebf, const float* __restrict__ rnorm,
                const float* __restrict__ mu, const float* __restrict__ sigma,
                float* __restrict__ pkq_part)
{
    __shared__ unsigned short q_buf[BQ * QSTR];   // 20992 B
    __shared__ float pkq_s[BQ * NK];
    __shared__ float rqs[BQ];

    const int tid  = threadIdx.x;
    const int lane = tid & 63;
    const int wv   = tid >> 6;
    const int b    = blockIdx.x & 255;    // XCD swizzle: both blocks of b share XCD b%8
    const int half = blockIdx.x >> 8;     // 0..1 (256 doc rows each)
    const int l16  = lane & 15;
    const int quad = lane >> 4;

    for (int i = tid; i < BQ * NK; i += 256) pkq_s[i] = 0.f;
    if (tid < BQ) rqs[tid] = rnorm[qtok[b * BQ + tid]];

    // this wave's d rows: step s -> row half*256 + s*64 + wv*16 + l16
    const int dbase = b * BD + half * 256 + wv * 16 + l16;
    int   td[4];
    float rd[4], dm[4];
    #pragma unroll
    for (int s = 0; s < 4; ++s) {
        td[s] = dtok[dbase + s * 64];
        rd[s] = rnorm[td[s]];
        dm[s] = (td[s] > 0) ? 1.f : 0.f;
    }

    // stage the 32 q rows once: 8 threads/row x 5 dwordx4 (pre-zero-padded)
    {
        int row = tid >> 3, part = tid & 7;
        int tok = qtok[b * BQ + row];
        const uint4* src = (const uint4*)(ebf + (size_t)tok * KPAD);
        #pragma unroll
        for (int i = 0; i < 5; ++i) {
            int c = part + i * 8;
            *(uint4*)&q_buf[row * QSTR + c * 8] = src[c];
        }
    }

    // prefetch step-0 B-fragments while the barrier drains
    shortx8 bf0[10], bf1[10];
    load_frags(bf0, ebf, td[0], quad);

    __syncthreads();

    // gaussian constants in SGPRs
    float mur[NK], cfr[NK];
    #pragma unroll
    for (int k = 0; k < NK; ++k) {
        float s = sbc(sigma[k]);
        mur[k] = sbc(mu[k]);
        cfr[k] = -0.5f / (s * s);
    }
    // q reciprocal norms for this lane's output rows
    float rqv[8];
    #pragma unroll
    for (int slab = 0; slab < 2; ++slab)
        #pragma unroll
        for (int r = 0; r < 4; ++r)
            rqv[slab * 4 + r] = rqs[slab * 16 + quad * 4 + r];

    const unsigned short* a0 = &q_buf[l16 * QSTR + quad * 8];
    const unsigned short* a1 = a0 + 16 * QSTR;

    float pk[2][4][NK];
    #pragma unroll
    for (int slab = 0; slab < 2; ++slab)
        #pragma unroll
        for (int r = 0; r < 4; ++r)
            #pragma unroll
            for (int k = 0; k < NK; ++k) pk[slab][r][k] = 0.f;

    #pragma unroll
    for (int s = 0; s < 4; ++s) {
        const shortx8* bf = (s & 1) ? bf1 : bf0;

        floatx4 acc0 = {0.f, 0.f, 0.f, 0.f};
        floatx4 acc1 = {0.f, 0.f, 0.f, 0.f};
        #pragma unroll
        for (int ks = 0; ks < 10; ++ks) {
            shortx8 aA = *(const shortx8*)(a0 + ks * 32);
            shortx8 aB = *(const shortx8*)(a1 + ks * 32);
            acc0 = __builtin_amdgcn_mfma_f32_16x16x32_bf16(aA, bf[ks], acc0, 0, 0, 0);
            acc1 = __builtin_amdgcn_mfma_f32_16x16x32_bf16(aB, bf[ks], acc1, 0, 0, 0);
        }

        // issue next step's loads BEFORE the exp tail (they land under it)
        if (s < 3) load_frags((s & 1) ? bf0 : bf1, ebf, td[s + 1], quad);

        #pragma unroll
        for (int slab = 0; slab < 2; ++slab) {
            floatx4 acc = slab ? acc1 : acc0;
            #pragma unroll
            for (int r = 0; r < 4; ++r) {
                float c0 = acc[r] * rqv[slab * 4 + r] * rd[s];
                #pragma unroll
                for (int k = 0; k < NK; ++k) {
                    float d0 = c0 - mur[k];
                    pk[slab][r][k] += dm[s] * __expf(cfr[k] * d0 * d0);
                }
            }
        }
    }

    // ONE cross-lane reduce (sum the 16 d-lanes of each quad) + LDS combine
    #pragma unroll
    for (int slab = 0; slab < 2; ++slab)
        #pragma unroll
        for (int r = 0; r < 4; ++r)
            #pragma unroll
            for (int k = 0; k < NK; ++k) {
                float v = pk[slab][r][k];
                v += __shfl_xor(v, 1);
                v += __shfl_xor(v, 2);
                v += __shfl_xor(v, 4);
                v += __shfl_xor(v, 8);
                if (l16 == 0)
                    atomicAdd(&pkq_s[(slab * 16 + quad * 4 + r) * NK + k], v);
            }
    __syncthreads();

    float* dst = pkq_part + (size_t)(b * 2 + half) * (BQ * NK);
    for (int i = tid; i < BQ * NK; i += 256) dst[i] = pkq_s[i];
}

// ---------------- Phase 3: epilogue ----------------
__global__ __launch_bounds__(64)
void knrm_epi(const int* __restrict__ qtok, const float* __restrict__ dw,
              const float* __restrict__ db, const float* __restrict__ pkq_part,
              float* __restrict__ out)
{
    int b = blockIdx.x, lane = threadIdx.x;
    float sq = 0.f;
    if (lane < BQ) {
        int tok = qtok[b * BQ + lane];
        if (tok > 0) {
            #pragma unroll
            for (int k = 0; k < NK; ++k) {
                float s = pkq_part[((size_t)(b * 2 + 0) * BQ + lane) * NK + k]
                        + pkq_part[((size_t)(b * 2 + 1) * BQ + lane) * NK + k];
                sq += __logf(fmaxf(s, 1e-10f)) * 0.01f * dw[k];
            }
        }
    }
    sq += __shfl_xor(sq, 1);
    sq += __shfl_xor(sq, 2);
    sq += __shfl_xor(sq, 4);
    sq += __shfl_xor(sq, 8);
    sq += __shfl_xor(sq, 16);
    sq += __shfl_xor(sq, 32);
    if (lane == 0) out[b] = sq + db[0];
}

extern "C" void kernel_launch(void* const* d_in, const int* in_sizes, int n_in,
                              void* d_out, int out_size, void* d_ws, size_t ws_size,
                              hipStream_t stream)
{
    const int*   qtok  = (const int*)d_in[0];
    const int*   dtok  = (const int*)d_in[1];
    const float* emb   = (const float*)d_in[2];
    const float* dw    = (const float*)d_in[3];
    const float* dbias = (const float*)d_in[4];
    const float* mu    = (const float*)d_in[5];
    const float* sg    = (const float*)d_in[6];
    float* out = (float*)d_out;

    const int V = in_sizes[2] / EDIM;   // 100000
    const size_t ebf_bytes = (size_t)V * KPAD * 2;   // 64 MB
    const size_t rn_bytes  = (size_t)V * 4;          // 0.4 MB

    unsigned short* ebf = (unsigned short*)d_ws;
    float* rnorm        = (float*)((char*)d_ws + ebf_bytes);
    float* pkq_part     = (float*)((char*)d_ws + ebf_bytes + rn_bytes);  // 720 KB

    knrm_norm<<<(V + 15) / 16, 256, 0, stream>>>(emb, ebf, rnorm, V);
    knrm_main6<<<B * 2, 256, 0, stream>>>(qtok, dtok, ebf, rnorm, mu, sg, pkq_part);
    knrm_epi<<<B, 64, 0, stream>>>(qtok, dw, dbias, pkq_part, out);
}

// Round 9
// 231.298 us; speedup vs baseline: 1.0743x; 1.0005x over previous
//
#include <hip/hip_runtime.h>

// KNRM round 9: three small knowns on top of R8's line-rate-optimal structure.
//  Model: scattered gather is bound by 64-B line-request rate (~27 G lines/s
//  chip-wide, consistent across R3/R4/R7/R8). d-row lines (1.31 M) are the
//  irreducible floor at bf16 (fp8/int8 fail the 3e-4 accuracy budget).
//  Phase 1 (knrm_norm): fp32 table -> bf16 rows padded to 320 cols + rnorm
//    from the ROUNDED values (exact-match cosine == 1; kernel0 sigma=1e-4).
//    Now 8 lanes/row with full uint4 stores (2x wider write path).
//  Phase 2 (knrm_main7): ONE 512-thread block per batch (grid 256). 8 waves,
//    each owns a 16-d-row lane-slice x 4 steps (R8 pipeline: register
//    double-buffered B-fragments, prefetch under the exp tail, Gaussian
//    partials in pk[2][4][11] registers, ONE cross-lane reduce at the end).
//    q staged to LDS once per BATCH (halves q lines vs R8). Epilogue fused:
//    log/mask/dot computed in-block from pkq_s -> out[b]. No partial buffer,
//    no epilogue kernel, no memset.

#define B      256
#define BQ     32
#define BD     512
#define EDIM   300
#define KPAD   320
#define NK     11
#define QSTR   328   // q_buf stride (halfwords): rows 16B-aligned

typedef float floatx4 __attribute__((ext_vector_type(4)));
typedef short shortx8 __attribute__((ext_vector_type(8)));

__device__ __forceinline__ unsigned short f2bf(float f) {
    unsigned int u = __float_as_uint(f);
    return (unsigned short)((u + 0x7fffu + ((u >> 16) & 1u)) >> 16);  // RNE
}
__device__ __forceinline__ float bf2f(unsigned short h) {
    return __uint_as_float(((unsigned int)h) << 16);
}
__device__ __forceinline__ float sbc(float x) {   // force into SGPR
    return __uint_as_float(__builtin_amdgcn_readfirstlane(__float_as_uint(x)));
}
__device__ __forceinline__ unsigned int pack2(float a, float b, float& ss) {
    unsigned short h0 = f2bf(a), h1 = f2bf(b);
    float g0 = bf2f(h0), g1 = bf2f(h1);
    ss += g0 * g0 + g1 * g1;
    return (unsigned int)h0 | ((unsigned int)h1 << 16);
}

// ---------------- Phase 1: normalize / convert table ----------------
// 8 lanes/row, 32 rows per 256-thread block, uint4 (16 B) stores.
__global__ __launch_bounds__(256)
void knrm_norm(const float* __restrict__ emb, unsigned short* __restrict__ ebf,
               float* __restrict__ rnorm, int V)
{
    int r    = blockIdx.x * 32 + (threadIdx.x >> 3);
    int part = threadIdx.x & 7;
    if (r >= V) return;
    const float4* src = (const float4*)(emb + (size_t)r * EDIM);
    uint4*        dst = (uint4*)(ebf + (size_t)r * KPAD);   // 40 x uint4 per row
    float ss = 0.f;
    #pragma unroll
    for (int i = 0; i < 5; ++i) {
        int j = part + i * 8;               // uint4 index 0..39
        uint4 o = {0u, 0u, 0u, 0u};
        if (j < 37) {                       // floats [8j, 8j+8) all < 296+... valid
            float4 a = src[2 * j];
            float4 c = src[2 * j + 1];
            o.x = pack2(a.x, a.y, ss);
            o.y = pack2(a.z, a.w, ss);
            o.z = pack2(c.x, c.y, ss);
            o.w = pack2(c.z, c.w, ss);
        } else if (j == 37) {               // floats 296..299 valid, 300..303 pad
            float4 a = src[74];
            o.x = pack2(a.x, a.y, ss);
            o.y = pack2(a.z, a.w, ss);
        }                                   // j = 38,39: all pad zeros
        dst[j] = o;
    }
    ss += __shfl_xor(ss, 1);
    ss += __shfl_xor(ss, 2);
    ss += __shfl_xor(ss, 4);
    if (part == 0) rnorm[r] = 1.f / (sqrtf(ss) + 1e-13f);
}

// ---------------- Phase 2: fused gather + MFMA + Gaussians + epilogue ----------------
__device__ __forceinline__ void load_frags(shortx8* bf, const unsigned short* __restrict__ ebf,
                                           int tok, int quad)
{
    const uint4* src = (const uint4*)(ebf + (size_t)tok * KPAD);
    #pragma unroll
    for (int ks = 0; ks < 10; ++ks)
        bf[ks] = *(const shortx8*)&src[quad + ks * 4];
}

__global__ __launch_bounds__(512, 2)
void knrm_main7(const int* __restrict__ qtok, const int* __restrict__ dtok,
                const unsigned short* __restrict__ ebf, const float* __restrict__ rnorm,
                const float* __restrict__ mu, const float* __restrict__ sigma,
                const float* __restrict__ dw, const float* __restrict__ db,
                float* __restrict__ out)
{
    __shared__ unsigned short q_buf[BQ * QSTR];   // 20992 B
    __shared__ float pkq_s[BQ * NK];
    __shared__ float rqs[BQ];
    __shared__ float red[BQ];

    const int tid  = threadIdx.x;
    const int lane = tid & 63;
    const int wv   = tid >> 6;            // 0..7
    const int b    = blockIdx.x;          // one block per batch
    const int l16  = lane & 15;
    const int quad = lane >> 4;

    for (int i = tid; i < BQ * NK; i += 512) pkq_s[i] = 0.f;
    if (tid < BQ) rqs[tid] = rnorm[qtok[b * BQ + tid]];

    // this wave's d rows: step s -> row s*128 + wv*16 + l16
    const int dbase = b * BD + wv * 16 + l16;
    int   td[4];
    float rd[4], dm[4];
    #pragma unroll
    for (int s = 0; s < 4; ++s) {
        td[s] = dtok[dbase + s * 128];
        rd[s] = rnorm[td[s]];
        dm[s] = (td[s] > 0) ? 1.f : 0.f;
    }

    // stage the 32 q rows once per batch: 16 threads/row, uint4 chunks
    {
        int row = tid >> 4, part = tid & 15;
        int tok = qtok[b * BQ + row];
        const uint4* src  = (const uint4*)(ebf + (size_t)tok * KPAD);
        uint4*       qrow = (uint4*)&q_buf[row * QSTR];
        for (int c = part; c < 40; c += 16) qrow[c] = src[c];
    }

    // prefetch step-0 B-fragments while the barrier drains
    shortx8 bf0[10], bf1[10];
    load_frags(bf0, ebf, td[0], quad);

    __syncthreads();

    float mur[NK], cfr[NK];
    #pragma unroll
    for (int k = 0; k < NK; ++k) {
        float s = sbc(sigma[k]);
        mur[k] = sbc(mu[k]);
        cfr[k] = -0.5f / (s * s);
    }
    float rqv[8];
    #pragma unroll
    for (int slab = 0; slab < 2; ++slab)
        #pragma unroll
        for (int r = 0; r < 4; ++r)
            rqv[slab * 4 + r] = rqs[slab * 16 + quad * 4 + r];

    const unsigned short* a0 = &q_buf[l16 * QSTR + quad * 8];
    const unsigned short* a1 = a0 + 16 * QSTR;

    float pk[2][4][NK];
    #pragma unroll
    for (int slab = 0; slab < 2; ++slab)
        #pragma unroll
        for (int r = 0; r < 4; ++r)
            #pragma unroll
            for (int k = 0; k < NK; ++k) pk[slab][r][k] = 0.f;

    #pragma unroll
    for (int s = 0; s < 4; ++s) {
        const shortx8* bf = (s & 1) ? bf1 : bf0;

        floatx4 acc0 = {0.f, 0.f, 0.f, 0.f};
        floatx4 acc1 = {0.f, 0.f, 0.f, 0.f};
        #pragma unroll
        for (int ks = 0; ks < 10; ++ks) {
            shortx8 aA = *(const shortx8*)(a0 + ks * 32);
            shortx8 aB = *(const shortx8*)(a1 + ks * 32);
            acc0 = __builtin_amdgcn_mfma_f32_16x16x32_bf16(aA, bf[ks], acc0, 0, 0, 0);
            acc1 = __builtin_amdgcn_mfma_f32_16x16x32_bf16(aB, bf[ks], acc1, 0, 0, 0);
        }

        // issue next step's loads BEFORE the exp tail (they land under it)
        if (s < 3) load_frags((s & 1) ? bf0 : bf1, ebf, td[s + 1], quad);

        #pragma unroll
        for (int slab = 0; slab < 2; ++slab) {
            floatx4 acc = slab ? acc1 : acc0;
            #pragma unroll
            for (int r = 0; r < 4; ++r) {
                float c0 = acc[r] * rqv[slab * 4 + r] * rd[s];
                #pragma unroll
                for (int k = 0; k < NK; ++k) {
                    float d0 = c0 - mur[k];
                    pk[slab][r][k] += dm[s] * __expf(cfr[k] * d0 * d0);
                }
            }
        }
    }

    // ONE cross-lane reduce (sum 16 d-lanes per quad) + LDS combine
    #pragma unroll
    for (int slab = 0; slab < 2; ++slab)
        #pragma unroll
        for (int r = 0; r < 4; ++r)
            #pragma unroll
            for (int k = 0; k < NK; ++k) {
                float v = pk[slab][r][k];
                v += __shfl_xor(v, 1);
                v += __shfl_xor(v, 2);
                v += __shfl_xor(v, 4);
                v += __shfl_xor(v, 8);
                if (l16 == 0)
                    atomicAdd(&pkq_s[(slab * 16 + quad * 4 + r) * NK + k], v);
            }
    __syncthreads();

    // fused epilogue: log/mask/dot -> out[b]
    if (tid < BQ) {
        int tok = qtok[b * BQ + tid];
        float sq = 0.f;
        if (tok > 0) {
            #pragma unroll
            for (int k = 0; k < NK; ++k) {
                float s = fmaxf(pkq_s[tid * NK + k], 1e-10f);
                sq += __logf(s) * 0.01f * dw[k];
            }
        }
        red[tid] = sq;
    }
    __syncthreads();
    if (tid == 0) {
        float s = db[0];
        #pragma unroll 8
        for (int i = 0; i < BQ; ++i) s += red[i];
        out[b] = s;
    }
}

extern "C" void kernel_launch(void* const* d_in, const int* in_sizes, int n_in,
                              void* d_out, int out_size, void* d_ws, size_t ws_size,
                              hipStream_t stream)
{
    const int*   qtok  = (const int*)d_in[0];
    const int*   dtok  = (const int*)d_in[1];
    const float* emb   = (const float*)d_in[2];
    const float* dw    = (const float*)d_in[3];
    const float* dbias = (const float*)d_in[4];
    const float* mu    = (const float*)d_in[5];
    const float* sg    = (const float*)d_in[6];
    float* out = (float*)d_out;

    const int V = in_sizes[2] / EDIM;   // 100000
    const size_t ebf_bytes = (size_t)V * KPAD * 2;   // 64 MB

    unsigned short* ebf = (unsigned short*)d_ws;
    float* rnorm        = (float*)((char*)d_ws + ebf_bytes);   // 0.4 MB

    knrm_norm<<<(V + 31) / 32, 256, 0, stream>>>(emb, ebf, rnorm, V);
    knrm_main7<<<B, 512, 0, stream>>>(qtok, dtok, ebf, rnorm, mu, sg, dw, dbias, out);
}

// Round 10
// 230.056 us; speedup vs baseline: 1.0801x; 1.0054x over previous
//
#include <hip/hip_runtime.h>

// KNRM round 10: R9 + referenced-row filtering for the norm pass.
//  Model (locked by R3-R9): main is MSHR/line-rate-bound (~27 G 64-B-lines/s
//  chip-wide, invariant to occupancy/traffic/roles); norm is streaming-BW
//  bound. Only byte/line cuts move anything. Last cut: only ~75% of vocab
//  rows are referenced by the 139k random tokens -> mark pass + skip.
//  Phase 0 (knrm_mark): flags[tok]=1 for all q/d tokens (~3 us).
//  Phase 1 (knrm_norm): fp32 -> bf16 rows (320-col zero-padded) + rnorm from
//    the ROUNDED values (exact-match cosine == 1; kernel0 sigma=1e-4 needs
//    this). Rows with flag==0 are skipped entirely (saves ~46 MB).
//  Phase 2 (knrm_main7): one 512-thr block per batch; 8 waves x 4 steps of
//    16 d rows; register double-buffered B-frags prefetched under the exp
//    tail; Gaussian partials in registers; ONE cross-lane reduce; fused
//    log/mask/dot epilogue. (Unchanged from R9 - at its line floor.)

#define B      256
#define BQ     32
#define BD     512
#define EDIM   300
#define KPAD   320
#define NK     11
#define QSTR   328   // q_buf stride (halfwords): rows 16B-aligned

typedef float floatx4 __attribute__((ext_vector_type(4)));
typedef short shortx8 __attribute__((ext_vector_type(8)));

__device__ __forceinline__ unsigned short f2bf(float f) {
    unsigned int u = __float_as_uint(f);
    return (unsigned short)((u + 0x7fffu + ((u >> 16) & 1u)) >> 16);  // RNE
}
__device__ __forceinline__ float bf2f(unsigned short h) {
    return __uint_as_float(((unsigned int)h) << 16);
}
__device__ __forceinline__ float sbc(float x) {   // force into SGPR
    return __uint_as_float(__builtin_amdgcn_readfirstlane(__float_as_uint(x)));
}
__device__ __forceinline__ unsigned int pack2(float a, float b, float& ss) {
    unsigned short h0 = f2bf(a), h1 = f2bf(b);
    float g0 = bf2f(h0), g1 = bf2f(h1);
    ss += g0 * g0 + g1 * g1;
    return (unsigned int)h0 | ((unsigned int)h1 << 16);
}

// ---------------- Phase 0: mark referenced vocab rows ----------------
__global__ __launch_bounds__(256)
void knrm_mark(const int* __restrict__ qtok, const int* __restrict__ dtok,
               unsigned char* __restrict__ flags)
{
    int i = blockIdx.x * 256 + threadIdx.x;
    const int NQ = B * BQ;              // 8192
    const int ND = B * BD;              // 131072
    if (i < NQ) flags[qtok[i]] = 1;
    else if (i < NQ + ND) flags[dtok[i - NQ]] = 1;
}

// ---------------- Phase 1: normalize / convert referenced rows ----------------
// 8 lanes/row, 32 rows per 256-thread block, uint4 (16 B) stores.
__global__ __launch_bounds__(256)
void knrm_norm(const float* __restrict__ emb, const unsigned char* __restrict__ flags,
               unsigned short* __restrict__ ebf, float* __restrict__ rnorm, int V)
{
    int r    = blockIdx.x * 32 + (threadIdx.x >> 3);
    int part = threadIdx.x & 7;
    if (r >= V) return;
    if (!flags[r]) return;              // unreferenced: never read by main
    const float4* src = (const float4*)(emb + (size_t)r * EDIM);
    uint4*        dst = (uint4*)(ebf + (size_t)r * KPAD);   // 40 x uint4 per row
    float ss = 0.f;
    #pragma unroll
    for (int i = 0; i < 5; ++i) {
        int j = part + i * 8;               // uint4 index 0..39
        uint4 o = {0u, 0u, 0u, 0u};
        if (j < 37) {
            float4 a = src[2 * j];
            float4 c = src[2 * j + 1];
            o.x = pack2(a.x, a.y, ss);
            o.y = pack2(a.z, a.w, ss);
            o.z = pack2(c.x, c.y, ss);
            o.w = pack2(c.z, c.w, ss);
        } else if (j == 37) {               // floats 296..299 valid, 300..303 pad
            float4 a = src[74];
            o.x = pack2(a.x, a.y, ss);
            o.y = pack2(a.z, a.w, ss);
        }                                   // j = 38,39: all pad zeros
        dst[j] = o;
    }
    ss += __shfl_xor(ss, 1);
    ss += __shfl_xor(ss, 2);
    ss += __shfl_xor(ss, 4);
    if (part == 0) rnorm[r] = 1.f / (sqrtf(ss) + 1e-13f);
}

// ---------------- Phase 2: fused gather + MFMA + Gaussians + epilogue ----------------
__device__ __forceinline__ void load_frags(shortx8* bf, const unsigned short* __restrict__ ebf,
                                           int tok, int quad)
{
    const uint4* src = (const uint4*)(ebf + (size_t)tok * KPAD);
    #pragma unroll
    for (int ks = 0; ks < 10; ++ks)
        bf[ks] = *(const shortx8*)&src[quad + ks * 4];
}

__global__ __launch_bounds__(512, 2)
void knrm_main7(const int* __restrict__ qtok, const int* __restrict__ dtok,
                const unsigned short* __restrict__ ebf, const float* __restrict__ rnorm,
                const float* __restrict__ mu, const float* __restrict__ sigma,
                const float* __restrict__ dw, const float* __restrict__ db,
                float* __restrict__ out)
{
    __shared__ unsigned short q_buf[BQ * QSTR];   // 20992 B
    __shared__ float pkq_s[BQ * NK];
    __shared__ float rqs[BQ];
    __shared__ float red[BQ];

    const int tid  = threadIdx.x;
    const int lane = tid & 63;
    const int wv   = tid >> 6;            // 0..7
    const int b    = blockIdx.x;          // one block per batch
    const int l16  = lane & 15;
    const int quad = lane >> 4;

    for (int i = tid; i < BQ * NK; i += 512) pkq_s[i] = 0.f;
    if (tid < BQ) rqs[tid] = rnorm[qtok[b * BQ + tid]];

    // this wave's d rows: step s -> row s*128 + wv*16 + l16
    const int dbase = b * BD + wv * 16 + l16;
    int   td[4];
    float rd[4], dm[4];
    #pragma unroll
    for (int s = 0; s < 4; ++s) {
        td[s] = dtok[dbase + s * 128];
        rd[s] = rnorm[td[s]];
        dm[s] = (td[s] > 0) ? 1.f : 0.f;
    }

    // stage the 32 q rows once per batch: 16 threads/row, uint4 chunks
    {
        int row = tid >> 4, part = tid & 15;
        int tok = qtok[b * BQ + row];
        const uint4* src  = (const uint4*)(ebf + (size_t)tok * KPAD);
        uint4*       qrow = (uint4*)&q_buf[row * QSTR];
        for (int c = part; c < 40; c += 16) qrow[c] = src[c];
    }

    // prefetch step-0 B-fragments while the barrier drains
    shortx8 bf0[10], bf1[10];
    load_frags(bf0, ebf, td[0], quad);

    __syncthreads();

    float mur[NK], cfr[NK];
    #pragma unroll
    for (int k = 0; k < NK; ++k) {
        float s = sbc(sigma[k]);
        mur[k] = sbc(mu[k]);
        cfr[k] = -0.5f / (s * s);
    }
    float rqv[8];
    #pragma unroll
    for (int slab = 0; slab < 2; ++slab)
        #pragma unroll
        for (int r = 0; r < 4; ++r)
            rqv[slab * 4 + r] = rqs[slab * 16 + quad * 4 + r];

    const unsigned short* a0 = &q_buf[l16 * QSTR + quad * 8];
    const unsigned short* a1 = a0 + 16 * QSTR;

    float pk[2][4][NK];
    #pragma unroll
    for (int slab = 0; slab < 2; ++slab)
        #pragma unroll
        for (int r = 0; r < 4; ++r)
            #pragma unroll
            for (int k = 0; k < NK; ++k) pk[slab][r][k] = 0.f;

    #pragma unroll
    for (int s = 0; s < 4; ++s) {
        const shortx8* bf = (s & 1) ? bf1 : bf0;

        floatx4 acc0 = {0.f, 0.f, 0.f, 0.f};
        floatx4 acc1 = {0.f, 0.f, 0.f, 0.f};
        #pragma unroll
        for (int ks = 0; ks < 10; ++ks) {
            shortx8 aA = *(const shortx8*)(a0 + ks * 32);
            shortx8 aB = *(const shortx8*)(a1 + ks * 32);
            acc0 = __builtin_amdgcn_mfma_f32_16x16x32_bf16(aA, bf[ks], acc0, 0, 0, 0);
            acc1 = __builtin_amdgcn_mfma_f32_16x16x32_bf16(aB, bf[ks], acc1, 0, 0, 0);
        }

        // issue next step's loads BEFORE the exp tail (they land under it)
        if (s < 3) load_frags((s & 1) ? bf0 : bf1, ebf, td[s + 1], quad);

        #pragma unroll
        for (int slab = 0; slab < 2; ++slab) {
            floatx4 acc = slab ? acc1 : acc0;
            #pragma unroll
            for (int r = 0; r < 4; ++r) {
                float c0 = acc[r] * rqv[slab * 4 + r] * rd[s];
                #pragma unroll
                for (int k = 0; k < NK; ++k) {
                    float d0 = c0 - mur[k];
                    pk[slab][r][k] += dm[s] * __expf(cfr[k] * d0 * d0);
                }
            }
        }
    }

    // ONE cross-lane reduce (sum 16 d-lanes per quad) + LDS combine
    #pragma unroll
    for (int slab = 0; slab < 2; ++slab)
        #pragma unroll
        for (int r = 0; r < 4; ++r)
            #pragma unroll
            for (int k = 0; k < NK; ++k) {
                float v = pk[slab][r][k];
                v += __shfl_xor(v, 1);
                v += __shfl_xor(v, 2);
                v += __shfl_xor(v, 4);
                v += __shfl_xor(v, 8);
                if (l16 == 0)
                    atomicAdd(&pkq_s[(slab * 16 + quad * 4 + r) * NK + k], v);
            }
    __syncthreads();

    // fused epilogue: log/mask/dot -> out[b]
    if (tid < BQ) {
        int tok = qtok[b * BQ + tid];
        float sq = 0.f;
        if (tok > 0) {
            #pragma unroll
            for (int k = 0; k < NK; ++k) {
                float s = fmaxf(pkq_s[tid * NK + k], 1e-10f);
                sq += __logf(s) * 0.01f * dw[k];
            }
        }
        red[tid] = sq;
    }
    __syncthreads();
    if (tid == 0) {
        float s = db[0];
        #pragma unroll 8
        for (int i = 0; i < BQ; ++i) s += red[i];
        out[b] = s;
    }
}

extern "C" void kernel_launch(void* const* d_in, const int* in_sizes, int n_in,
                              void* d_out, int out_size, void* d_ws, size_t ws_size,
                              hipStream_t stream)
{
    const int*   qtok  = (const int*)d_in[0];
    const int*   dtok  = (const int*)d_in[1];
    const float* emb   = (const float*)d_in[2];
    const float* dw    = (const float*)d_in[3];
    const float* dbias = (const float*)d_in[4];
    const float* mu    = (const float*)d_in[5];
    const float* sg    = (const float*)d_in[6];
    float* out = (float*)d_out;

    const int V = in_sizes[2] / EDIM;   // 100000
    const size_t ebf_bytes = (size_t)V * KPAD * 2;   // 64 MB
    const size_t rn_bytes  = (size_t)((V * 4 + 255) & ~255);

    unsigned short* ebf   = (unsigned short*)d_ws;
    float*          rnorm = (float*)((char*)d_ws + ebf_bytes);
    unsigned char*  flags = (unsigned char*)((char*)d_ws + ebf_bytes + rn_bytes);

    hipMemsetAsync(flags, 0, V, stream);
    const int ntok = B * BQ + B * BD;   // 139264
    knrm_mark<<<(ntok + 255) / 256, 256, 0, stream>>>(qtok, dtok, flags);
    knrm_norm<<<(V + 31) / 32, 256, 0, stream>>>(emb, flags, ebf, rnorm, V);
    knrm_main7<<<B, 512, 0, stream>>>(qtok, dtok, ebf, rnorm, mu, sg, dw, dbias, out);
}